// Round 10
// baseline (294.527 us; speedup 1.0000x reference)
//
#include <hip/hip_runtime.h>
#include <hip/hip_bf16.h>
#include <stdint.h>

typedef __hip_bfloat16 bf16;
typedef __attribute__((ext_vector_type(8))) short short8;    // 8 bf16 (4 VGPRs) MFMA A/B frag
typedef __attribute__((ext_vector_type(4))) float f32x4;     // 16x16 C/D frag
typedef __attribute__((ext_vector_type(16))) float f32x16;   // 32x32 C/D frag

#define MFMA16(a, b, c) __builtin_amdgcn_mfma_f32_16x16x32_bf16((a), (b), (c), 0, 0, 0)
#define MFMA32(a, b, c) __builtin_amdgcn_mfma_f32_32x32x16_bf16((a), (b), (c), 0, 0, 0)

__device__ __forceinline__ unsigned short f2bf(float f) {
  bf16 h = __float2bfloat16(f);
  unsigned short u;
  __builtin_memcpy(&u, &h, 2);
  return u;
}

__device__ __forceinline__ uint32_t cvtpk(float lo, float hi) {
  uint32_t r;
  asm("v_cvt_pk_bf16_f32 %0, %1, %2" : "=v"(r) : "v"(lo), "v"(hi));
  return r;
}

// v_permlane32_swap_b32 a, b : a.lanes[32:63] <-> b.lanes[0:31]
__device__ __forceinline__ void pl32swap(uint32_t& a, uint32_t& b) {
  asm volatile("v_permlane32_swap_b32 %0, %1" : "+v"(a), "+v"(b));
}

__device__ __forceinline__ void gload_lds16(const void* g, void* l) {
  __builtin_amdgcn_global_load_lds(
      (const __attribute__((address_space(1))) uint32_t*)g,
      (__attribute__((address_space(3))) uint32_t*)l, 16, 0, 0);
}

// 128B-row XOR swizzle: 16B chunk c of row r lives at chunk (c ^ (r & 7)).
__device__ __forceinline__ int swz_chunk(int row, int c) { return c ^ (row & 7); }

// ---------------------------------------------------------------- convert ----
// x (1572864 float4) + 4 weights (147456 float4 each) in ONE launch.
__global__ __launch_bounds__(256) void cvt_all(
    const float* __restrict__ x,
    const float* __restrict__ w0, const float* __restrict__ w1,
    const float* __restrict__ w2, const float* __restrict__ w3,
    bf16* __restrict__ xo,
    bf16* __restrict__ o0, bf16* __restrict__ o1,
    bf16* __restrict__ o2, bf16* __restrict__ o3) {
  int idx = blockIdx.x * 256 + threadIdx.x;     // 0..2162687
  const float* src;
  bf16* dst;
  int i;
  if (idx < 1572864) {
    src = x; dst = xo; i = idx;
  } else {
    int r = idx - 1572864;
    int w = r / 147456;
    i = r - w * 147456;
    src = (w == 0) ? w0 : (w == 1) ? w1 : (w == 2) ? w2 : w3;
    dst = (w == 0) ? o0 : (w == 1) ? o1 : (w == 2) ? o2 : o3;
  }
  float4 v = ((const float4*)src)[i];
  ushort4 u;
  u.x = f2bf(v.x); u.y = f2bf(v.y); u.z = f2bf(v.z); u.w = f2bf(v.w);
  ((ushort4*)dst)[i] = u;
}

// --------------------------------------------------------- fused QKV GEMM ----
// BK=64, XOR-swizzled LDS (pre-swizzled DMA source + swizzled frag reads).
// blockIdx.y 0..17; y/6 selects {Q,K,V}.
__global__ __launch_bounds__(256, 4) void gemm_qkv(
    const bf16* __restrict__ A,
    const bf16* __restrict__ Wqb, const bf16* __restrict__ Wkb,
    const bf16* __restrict__ Wvb,
    const float* __restrict__ bq, const float* __restrict__ bk,
    const float* __restrict__ bv,
    bf16* __restrict__ Qh, bf16* __restrict__ Kh, bf16* __restrict__ Vh,
    float sq) {
  __shared__ bf16 As[128 * 64];   // 16KB, swizzled
  __shared__ bf16 Bs[128 * 64];
  const int tid = threadIdx.x;
  const int lane = tid & 63, wid = tid >> 6;
  const int wr = wid >> 1, wc = wid & 1;
  const int l15 = lane & 15, lhi = lane >> 4;
  const int tm = blockIdx.x * 128;
  const int by = blockIdx.y;
  const int seg = by / 6;                 // 0=Q 1=K 2=V
  const int tn = (by - seg * 6) * 128;

  const bf16* B = (seg == 0) ? Wqb : (seg == 1) ? Wkb : Wvb;
  const float* bias = (seg == 0) ? bq : (seg == 1) ? bk : bv;
  bf16* dst = (seg == 0) ? Qh : (seg == 1) ? Kh : Vh;
  const float scale = (seg == 0) ? sq : 1.0f;
  const int K = 768;

  f32x4 zero = {0.f, 0.f, 0.f, 0.f};
  f32x4 acc[4][4];
  for (int i = 0; i < 4; ++i)
    for (int j = 0; j < 4; ++j) acc[i][j] = zero;

  for (int k0 = 0; k0 < K; k0 += 64) {
    __syncthreads();
    for (int it = 0; it < 4; ++it) {
      int o = (tid + it * 256) << 4;              // 0..16K-16
      int row = o >> 7, c = (o >> 4) & 7;
      int sw = swz_chunk(row, c) << 4;            // pre-swizzled source chunk
      gload_lds16((const char*)A + (((size_t)(tm + row) * K + k0) << 1) + sw, (char*)As + o);
      gload_lds16((const char*)B + (((size_t)(tn + row) * K + k0) << 1) + sw, (char*)Bs + o);
    }
    __syncthreads();
    for (int ks = 0; ks < 2; ++ks) {
      short8 af[4], bfr[4];
      for (int mi = 0; mi < 4; ++mi) {
        int row = wr * 64 + mi * 16 + l15;
        af[mi] = *(const short8*)((const char*)As + row * 128 +
                                  (swz_chunk(row, ks * 4 + lhi) << 4));
      }
      for (int ni = 0; ni < 4; ++ni) {
        int row = wc * 64 + ni * 16 + l15;
        bfr[ni] = *(const short8*)((const char*)Bs + row * 128 +
                                   (swz_chunk(row, ks * 4 + lhi) << 4));
      }
      for (int mi = 0; mi < 4; ++mi)
        for (int ni = 0; ni < 4; ++ni)
          acc[mi][ni] = MFMA16(af[mi], bfr[ni], acc[mi][ni]);
    }
  }

  for (int mi = 0; mi < 4; ++mi)
    for (int ni = 0; ni < 4; ++ni)
      for (int j = 0; j < 4; ++j) {
        int m = tm + wr * 64 + mi * 16 + lhi * 4 + j;   // token index
        int n = tn + wc * 64 + ni * 16 + l15;           // 0..767 within segment
        float v = (acc[mi][ni][j] + bias[n]) * scale;
        int b = m >> 12, s = m & 4095, h = n >> 6, d = n & 63;
        dst[(((size_t)(b * 12 + h) * 4096 + s) << 6) + d] = __float2bfloat16(v);
      }
}

// ------------------------------------------------------------ out-proj GEMM --
// 128x64 tiles, BK=64, swizzled LDS as above.
__global__ __launch_bounds__(256, 4) void gemm_wo(
    const bf16* __restrict__ A, const bf16* __restrict__ B,
    const float* __restrict__ bias, float* __restrict__ C) {
  __shared__ bf16 As[128 * 64];   // 16KB
  __shared__ bf16 Bs[64 * 64];    // 8KB
  const int tid = threadIdx.x;
  const int lane = tid & 63, wid = tid >> 6;
  const int l15 = lane & 15, lhi = lane >> 4;
  const int tm = blockIdx.x * 128, tn = blockIdx.y * 64;
  const int K = 768;

  f32x4 zero = {0.f, 0.f, 0.f, 0.f};
  f32x4 acc[2][4];
  for (int i = 0; i < 2; ++i)
    for (int j = 0; j < 4; ++j) acc[i][j] = zero;

  for (int k0 = 0; k0 < K; k0 += 64) {
    __syncthreads();
    for (int it = 0; it < 4; ++it) {
      int o = (tid + it * 256) << 4;
      int row = o >> 7, c = (o >> 4) & 7;
      int sw = swz_chunk(row, c) << 4;
      gload_lds16((const char*)A + (((size_t)(tm + row) * K + k0) << 1) + sw, (char*)As + o);
    }
    for (int it = 0; it < 2; ++it) {
      int o = (tid + it * 256) << 4;              // 0..8K-16
      int row = o >> 7, c = (o >> 4) & 7;
      int sw = swz_chunk(row, c) << 4;
      gload_lds16((const char*)B + (((size_t)(tn + row) * K + k0) << 1) + sw, (char*)Bs + o);
    }
    __syncthreads();
    for (int ks = 0; ks < 2; ++ks) {
      short8 af[2], bfr[4];
      for (int mi = 0; mi < 2; ++mi) {
        int row = wid * 32 + mi * 16 + l15;
        af[mi] = *(const short8*)((const char*)As + row * 128 +
                                  (swz_chunk(row, ks * 4 + lhi) << 4));
      }
      for (int ni = 0; ni < 4; ++ni) {
        int row = ni * 16 + l15;
        bfr[ni] = *(const short8*)((const char*)Bs + row * 128 +
                                   (swz_chunk(row, ks * 4 + lhi) << 4));
      }
      for (int mi = 0; mi < 2; ++mi)
        for (int ni = 0; ni < 4; ++ni)
          acc[mi][ni] = MFMA16(af[mi], bfr[ni], acc[mi][ni]);
    }
  }

  for (int mi = 0; mi < 2; ++mi)
    for (int ni = 0; ni < 4; ++ni)
      for (int j = 0; j < 4; ++j) {
        int m = tm + wid * 32 + mi * 16 + lhi * 4 + j;
        int n = tn + ni * 16 + l15;
        C[(size_t)m * 768 + n] = acc[mi][ni][j] + bias[n];
      }
}

// ------------------------------------------------------------- V transpose ---
// Vh [bh][4096][64] -> VTh [bh][64][4096], 64-token tiles. Write side packs
// token-pairs as b32 (round-5-verified mapping), halving LDS write instrs.
__global__ __launch_bounds__(256) void transpose_v(const bf16* __restrict__ Vh,
                                                   bf16* __restrict__ VTh) {
  __shared__ bf16 T[64 * 64];   // [d][kv] swizzled 16B chunks
  const int tid = threadIdx.x;
  const int bh = blockIdx.x >> 6;        // 0..23
  const int t = blockIdx.x & 63;         // token tile
  const char* src = (const char*)(Vh + ((size_t)bh * 4096 + t * 64) * 64);
  char* dst = (char*)(VTh + ((size_t)bh * 64) * 4096 + t * 64);

  const int rp = tid & 31, cc = tid >> 5;   // row-pair, d-chunk
  uint4 va = *(const uint4*)(src + (2 * rp) * 128 + cc * 16);
  uint4 vb = *(const uint4*)(src + (2 * rp + 1) * 128 + cc * 16);
  unsigned short a16[8], b16[8];
  __builtin_memcpy(a16, &va, 16);
  __builtin_memcpy(b16, &vb, 16);
#pragma unroll
  for (int jj = 0; jj < 8; ++jj) {
    uint32_t w = (uint32_t)a16[jj] | ((uint32_t)b16[jj] << 16);
    *(uint32_t*)((char*)T + (cc * 8 + jj) * 128 + (((rp >> 2) ^ jj) << 4) +
                 ((rp & 3) << 2)) = w;
  }
  __syncthreads();
  for (int it = 0; it < 2; ++it) {
    int idx = tid + it * 256;
    int d = idx >> 3, c = idx & 7;       // tokens c*8..c*8+7 of row d
    uint4 vv = *(const uint4*)((const char*)T + d * 128 + (swz_chunk(d, c) << 4));
    *(uint4*)(dst + (size_t)d * 8192 + c * 16) = vv;
  }
}

// --------------------------------------------------------------- attention ---
// Round-9 structure + T15 double-pipeline: per-wave order is
//   QK[t] -> PV[t-1] (MFMA pipe) -> exp/cvt[t] (VALU/trans pipe)
// so softmax of tile t overlaps PV of t-1. V is TRIPLE-buffered (PV[t-1]
// reads V[t-1] while V[t+1] stages); K stays double-buffered. One barrier
// per tile; PV epilogue + barrier before the OX cross-wave exchange.
__global__ __launch_bounds__(256, 3) void attn_kernel(
    const bf16* __restrict__ Qh, const bf16* __restrict__ Kh,
    const bf16* __restrict__ VTh, bf16* __restrict__ AO) {
  __shared__ float4 smem4[40960 / 16];   // K 2x8K @0 | V 3x8K @16K ; OX union
  char* smraw = (char*)smem4;
#define KTB(b) (smraw + (b) * 8192)
#define VTB(b) (smraw + 16384 + (b) * 8192)
  float* OX = (float*)smraw;             // [2 qsub][64 lane][68] (epilogue only)

  const int tid = threadIdx.x;
  const int lane = tid & 63, wid = tid >> 6;
  const int l31 = lane & 31, h = lane >> 5;
  const int qsub = wid & 1, kvh = wid >> 1;

  const int bh = blockIdx.x >> 5;        // 0..23 = b*12+head
  const int qt = blockIdx.x & 31;

  const size_t hb = (size_t)bh * 4096 * 64;
  const bf16* Qb = Qh + hb;
  const bf16* Kb = Kh + hb;
  const char* Vg0 = (const char*)(VTh + hb);   // V^T: row d stride 8192 B
  const int qb = qt * 128 + qsub * 64;

  short8 qf[2][4];
#pragma unroll
  for (int j = 0; j < 2; ++j)
#pragma unroll
    for (int ki = 0; ki < 4; ++ki)
      qf[j][ki] = *(const short8*)((const char*)Qb + (size_t)(qb + 32 * j + l31) * 128 +
                                   ki * 32 + h * 16);

  f32x16 z16;
  for (int i = 0; i < 16; ++i) z16[i] = 0.f;
  f32x16 o00 = z16, o01 = z16, o10 = z16, o11 = z16;
  float psum0 = 0.f, psum1 = 0.f;

  const int krow = kvh * 32 + l31;

  // staging helper offsets (per thread): two 16B chunks of an 8KB tile
#define STAGE_K(gbase, dstb)                                             \
  for (int it = 0; it < 2; ++it) {                                       \
    int o = (tid + it * 256) << 4;                                       \
    int row = o >> 7, c = (o >> 4) & 7;                                  \
    gload_lds16((gbase) + row * 128 + (swz_chunk(row, c) << 4), (dstb) + o); \
  }
#define STAGE_V(gbase, dstb)                                             \
  for (int it = 0; it < 2; ++it) {                                       \
    int o = (tid + it * 256) << 4;                                       \
    int row = o >> 7, c = (o >> 4) & 7;                                  \
    gload_lds16((gbase) + row * 8192 + (swz_chunk(row, c) << 4), (dstb) + o); \
  }

  // QK: produces s0 (kv kvh*32+..), s1 for the two q-frags
#define DO_QK(Kl)                                                        \
  {                                                                      \
    short8 kf = *(const short8*)((Kl) + krow * 128 + (swz_chunk(krow, h) << 4)); \
    s0 = MFMA32(kf, qf[0][0], z16);                                      \
    s1 = MFMA32(kf, qf[1][0], z16);                                      \
  }                                                                      \
  _Pragma("unroll")                                                      \
  for (int ki = 1; ki < 4; ++ki) {                                       \
    short8 kf = *(const short8*)((Kl) + krow * 128 + (swz_chunk(krow, 2 * ki + h) << 4)); \
    s0 = MFMA32(kf, qf[0][ki], s0);                                      \
    s1 = MFMA32(kf, qf[1][ki], s1);                                      \
  }

#define DO_PV(Vl)                                                        \
  _Pragma("unroll")                                                      \
  for (int kk = 0; kk < 2; ++kk) {                                       \
    short8 v0 = *(const short8*)((Vl) + l31 * 128 +                      \
                                 (swz_chunk(l31, 4 * kvh + 2 * kk + h) << 4)); \
    short8 v1 = *(const short8*)((Vl) + (32 + l31) * 128 +               \
                                 (swz_chunk(32 + l31, 4 * kvh + 2 * kk + h) << 4)); \
    o00 = MFMA32(v0, pb[0][kk], o00);                                    \
    o01 = MFMA32(v0, pb[1][kk], o01);                                    \
    o10 = MFMA32(v1, pb[0][kk], o10);                                    \
    o11 = MFMA32(v1, pb[1][kk], o11);                                    \
  }

#define DO_EXP()                                                         \
  _Pragma("unroll")                                                      \
  for (int j = 0; j < 2; ++j) {                                          \
    _Pragma("unroll")                                                    \
    for (int kk = 0; kk < 2; ++kk) {                                     \
      float p[8];                                                        \
      _Pragma("unroll")                                                  \
      for (int e = 0; e < 8; ++e)                                        \
        p[e] = __builtin_amdgcn_exp2f(j ? s1[8 * kk + e] : s0[8 * kk + e]); \
      float ps = ((p[0] + p[1]) + (p[2] + p[3])) + ((p[4] + p[5]) + (p[6] + p[7])); \
      if (j) psum1 += ps; else psum0 += ps;                              \
      uint32_t A0 = cvtpk(p[0], p[1]), A1 = cvtpk(p[2], p[3]);           \
      uint32_t B0 = cvtpk(p[4], p[5]), B1 = cvtpk(p[6], p[7]);           \
      pl32swap(A0, B0);                                                  \
      pl32swap(A1, B1);                                                  \
      uint32_t w_[4] = {A0, A1, B0, B1};                                 \
      short8 frag;                                                       \
      __builtin_memcpy(&frag, w_, 16);                                   \
      pb[j][kk] = frag;                                                  \
    }                                                                    \
  }

  short8 pb[2][2];

  // ---- prologue: stage tile 0; barrier; stage tile 1; QK[0]; exp[0]
  STAGE_K((const char*)Kb, KTB(0));
  STAGE_V(Vg0, VTB(0));
  __syncthreads();
  STAGE_K((const char*)(Kb + (size_t)4096), KTB(1));
  STAGE_V(Vg0 + (size_t)128, VTB(1));
  {
    f32x16 s0, s1;
    DO_QK(KTB(0));
    DO_EXP();
  }

  char* Vp = VTB(0);   // V[t-1]
  char* Vc = VTB(1);   // V[t]
  char* Vn = VTB(2);   // V[t+1] staging
  for (int kt = 1; kt < 64; ++kt) {
    __syncthreads();   // K[kt], V[kt] staged; all reads of K[kt-1], V[kt-2] done
    if (kt < 63) {
      STAGE_K((const char*)(Kb + (size_t)(kt + 1) * 4096), KTB((kt + 1) & 1));
      STAGE_V(Vg0 + (size_t)(kt + 1) * 128, Vn);
    }
    f32x16 s0, s1;
    __builtin_amdgcn_s_setprio(1);
    DO_QK(KTB(kt & 1));
    DO_PV(Vp);         // tile kt-1, overlaps with exp below on MFMA pipe
    __builtin_amdgcn_s_setprio(0);
    DO_EXP();          // tile kt -> pb (VALU/trans, overlaps PV execution)
    char* t = Vp; Vp = Vc; Vc = Vn; Vn = t;
  }
  DO_PV(Vp);           // tile 63 (Vp now = V[63])
  __syncthreads();     // all V reads done before OX overwrites LDS

  psum0 += __shfl_xor(psum0, 32);
  psum1 += __shfl_xor(psum1, 32);

  float* W = OX + (size_t)(qsub * 64 + lane) * 68;
  if (kvh == 1) {
#pragma unroll
    for (int g = 0; g < 4; ++g) {
      *(float4*)(W + 0 * 16 + 4 * g) = make_float4(o00[4*g], o00[4*g+1], o00[4*g+2], o00[4*g+3]);
      *(float4*)(W + 1 * 16 + 4 * g) = make_float4(o01[4*g], o01[4*g+1], o01[4*g+2], o01[4*g+3]);
      *(float4*)(W + 2 * 16 + 4 * g) = make_float4(o10[4*g], o10[4*g+1], o10[4*g+2], o10[4*g+3]);
      *(float4*)(W + 3 * 16 + 4 * g) = make_float4(o11[4*g], o11[4*g+1], o11[4*g+2], o11[4*g+3]);
    }
    W[64] = psum0;
    W[65] = psum1;
  }
  __syncthreads();
  if (kvh == 0) {
#pragma unroll
    for (int g = 0; g < 4; ++g) {
      float4 a0 = *(const float4*)(W + 0 * 16 + 4 * g);
      float4 a1 = *(const float4*)(W + 1 * 16 + 4 * g);
      float4 a2 = *(const float4*)(W + 2 * 16 + 4 * g);
      float4 a3 = *(const float4*)(W + 3 * 16 + 4 * g);
      o00[4*g] += a0.x; o00[4*g+1] += a0.y; o00[4*g+2] += a0.z; o00[4*g+3] += a0.w;
      o01[4*g] += a1.x; o01[4*g+1] += a1.y; o01[4*g+2] += a1.z; o01[4*g+3] += a1.w;
      o10[4*g] += a2.x; o10[4*g+1] += a2.y; o10[4*g+2] += a2.z; o10[4*g+3] += a2.w;
      o11[4*g] += a3.x; o11[4*g+1] += a3.y; o11[4*g+2] += a3.z; o11[4*g+3] += a3.w;
    }
    psum0 += W[64];
    psum1 += W[65];
    float pinv0 = 1.0f / psum0;
    float pinv1 = 1.0f / psum1;

    const int b = bh / 12, hd = bh % 12;
#pragma unroll
    for (int j = 0; j < 2; ++j) {
      int q = qb + 32 * j + l31;
      char* base = (char*)AO + (((size_t)(b * 4096 + q)) * 768 + hd * 64) * 2;
      float pv = j ? pinv1 : pinv0;
#pragma unroll
      for (int t = 0; t < 2; ++t) {
#pragma unroll
        for (int u = 0; u < 4; ++u) {
          ushort4 us;
          float v0 = (t ? (j ? o11[4*u+0] : o10[4*u+0]) : (j ? o01[4*u+0] : o00[4*u+0]));
          float v1 = (t ? (j ? o11[4*u+1] : o10[4*u+1]) : (j ? o01[4*u+1] : o00[4*u+1]));
          float v2 = (t ? (j ? o11[4*u+2] : o10[4*u+2]) : (j ? o01[4*u+2] : o00[4*u+2]));
          float v3 = (t ? (j ? o11[4*u+3] : o10[4*u+3]) : (j ? o01[4*u+3] : o00[4*u+3]));
          us.x = f2bf(v0 * pv);
          us.y = f2bf(v1 * pv);
          us.z = f2bf(v2 * pv);
          us.w = f2bf(v3 * pv);
          int d0 = 32 * t + 8 * u + 4 * h;
          *(ushort4*)(base + d0 * 2) = us;
        }
      }
    }
  }
#undef KTB
#undef VTB
#undef STAGE_K
#undef STAGE_V
#undef DO_QK
#undef DO_PV
#undef DO_EXP
}

// ------------------------------------------------------------------ launch ---
extern "C" void kernel_launch(void* const* d_in, const int* in_sizes, int n_in,
                              void* d_out, int out_size, void* d_ws, size_t ws_size,
                              hipStream_t stream) {
  (void)in_sizes; (void)n_in; (void)out_size; (void)ws_size;
  const float* x  = (const float*)d_in[0];
  const float* Wq = (const float*)d_in[1];
  const float* bq = (const float*)d_in[2];
  const float* Wk = (const float*)d_in[3];
  const float* bk = (const float*)d_in[4];
  const float* Wv = (const float*)d_in[5];
  const float* bv = (const float*)d_in[6];
  const float* Wo = (const float*)d_in[7];
  const float* bo = (const float*)d_in[8];

  char* ws = (char*)d_ws;
  bf16* Qh  = (bf16*)(ws + 0);           // [24][4096][64]
  bf16* Kh  = (bf16*)(ws + 12582912);
  bf16* Vh  = (bf16*)(ws + 25165824);    // V head-split; later reused as AO
  bf16* xb  = (bf16*)(ws + 37748736);    // x bf16; later reused as V^T
  bf16* Wqb = (bf16*)(ws + 50331648);
  bf16* Wkb = (bf16*)(ws + 51511296);
  bf16* Wvb = (bf16*)(ws + 52690944);
  bf16* Wob = (bf16*)(ws + 53870592);    // end ~55.05 MB
  bf16* VTh = xb;                        // V^T [24][64][4096] (xb dead then)
  bf16* AO  = Vh;                        // attn out (Vh dead then)

  cvt_all<<<8448, 256, 0, stream>>>(x, Wq, Wk, Wv, Wo, xb, Wqb, Wkb, Wvb, Wob);

  const float SQ = 0.125f * 1.4426950408889634f;  // 1/sqrt(64) * log2(e)
  dim3 gq(64, 18);
  gemm_qkv<<<gq, 256, 0, stream>>>(xb, Wqb, Wkb, Wvb, bq, bk, bv,
                                   Qh, Kh, Vh, SQ);
  transpose_v<<<1536, 256, 0, stream>>>(Vh, VTh);
  attn_kernel<<<768, 256, 0, stream>>>(Qh, Kh, VTh, AO);
  dim3 gw(64, 12);
  gemm_wo<<<gw, 256, 0, stream>>>(AO, Wob, bo, (float*)d_out);
}

// Round 11
// 187.908 us; speedup vs baseline: 1.5674x; 1.5674x over previous
//
#include <hip/hip_runtime.h>
#include <hip/hip_bf16.h>
#include <stdint.h>

typedef __hip_bfloat16 bf16;
typedef __attribute__((ext_vector_type(8))) short short8;    // 8 bf16 (4 VGPRs) MFMA A/B frag
typedef __attribute__((ext_vector_type(4))) float f32x4;     // 16x16 C/D frag
typedef __attribute__((ext_vector_type(16))) float f32x16;   // 32x32 C/D frag

#define MFMA16(a, b, c) __builtin_amdgcn_mfma_f32_16x16x32_bf16((a), (b), (c), 0, 0, 0)
#define MFMA32(a, b, c) __builtin_amdgcn_mfma_f32_32x32x16_bf16((a), (b), (c), 0, 0, 0)

__device__ __forceinline__ unsigned short f2bf(float f) {
  bf16 h = __float2bfloat16(f);
  unsigned short u;
  __builtin_memcpy(&u, &h, 2);
  return u;
}

__device__ __forceinline__ uint32_t cvtpk(float lo, float hi) {
  uint32_t r;
  asm("v_cvt_pk_bf16_f32 %0, %1, %2" : "=v"(r) : "v"(lo), "v"(hi));
  return r;
}

// v_permlane32_swap_b32 a, b : a.lanes[32:63] <-> b.lanes[0:31]
__device__ __forceinline__ void pl32swap(uint32_t& a, uint32_t& b) {
  asm volatile("v_permlane32_swap_b32 %0, %1" : "+v"(a), "+v"(b));
}

__device__ __forceinline__ void gload_lds16(const void* g, void* l) {
  __builtin_amdgcn_global_load_lds(
      (const __attribute__((address_space(1))) uint32_t*)g,
      (__attribute__((address_space(3))) uint32_t*)l, 16, 0, 0);
}

// 128B-row XOR swizzle: 16B chunk c of row r lives at chunk (c ^ (r & 7)).
__device__ __forceinline__ int swz_chunk(int row, int c) { return c ^ (row & 7); }

// ---------------------------------------------------------------- convert ----
// x (1572864 float4) + 4 weights (147456 float4 each) in ONE launch.
__global__ __launch_bounds__(256) void cvt_all(
    const float* __restrict__ x,
    const float* __restrict__ w0, const float* __restrict__ w1,
    const float* __restrict__ w2, const float* __restrict__ w3,
    bf16* __restrict__ xo,
    bf16* __restrict__ o0, bf16* __restrict__ o1,
    bf16* __restrict__ o2, bf16* __restrict__ o3) {
  int idx = blockIdx.x * 256 + threadIdx.x;     // 0..2162687
  const float* src;
  bf16* dst;
  int i;
  if (idx < 1572864) {
    src = x; dst = xo; i = idx;
  } else {
    int r = idx - 1572864;
    int w = r / 147456;
    i = r - w * 147456;
    src = (w == 0) ? w0 : (w == 1) ? w1 : (w == 2) ? w2 : w3;
    dst = (w == 0) ? o0 : (w == 1) ? o1 : (w == 2) ? o2 : o3;
  }
  float4 v = ((const float4*)src)[i];
  ushort4 u;
  u.x = f2bf(v.x); u.y = f2bf(v.y); u.z = f2bf(v.z); u.w = f2bf(v.w);
  ((ushort4*)dst)[i] = u;
}

// --------------------------------------------------------- fused QKV GEMM ----
// BK=64, XOR-swizzled LDS (pre-swizzled DMA source + swizzled frag reads).
// blockIdx.y 0..17; y/6 selects {Q,K,V}.
__global__ __launch_bounds__(256, 4) void gemm_qkv(
    const bf16* __restrict__ A,
    const bf16* __restrict__ Wqb, const bf16* __restrict__ Wkb,
    const bf16* __restrict__ Wvb,
    const float* __restrict__ bq, const float* __restrict__ bk,
    const float* __restrict__ bv,
    bf16* __restrict__ Qh, bf16* __restrict__ Kh, bf16* __restrict__ Vh,
    float sq) {
  __shared__ bf16 As[128 * 64];   // 16KB, swizzled
  __shared__ bf16 Bs[128 * 64];
  const int tid = threadIdx.x;
  const int lane = tid & 63, wid = tid >> 6;
  const int wr = wid >> 1, wc = wid & 1;
  const int l15 = lane & 15, lhi = lane >> 4;
  const int tm = blockIdx.x * 128;
  const int by = blockIdx.y;
  const int seg = by / 6;                 // 0=Q 1=K 2=V
  const int tn = (by - seg * 6) * 128;

  const bf16* B = (seg == 0) ? Wqb : (seg == 1) ? Wkb : Wvb;
  const float* bias = (seg == 0) ? bq : (seg == 1) ? bk : bv;
  bf16* dst = (seg == 0) ? Qh : (seg == 1) ? Kh : Vh;
  const float scale = (seg == 0) ? sq : 1.0f;
  const int K = 768;

  f32x4 zero = {0.f, 0.f, 0.f, 0.f};
  f32x4 acc[4][4];
  for (int i = 0; i < 4; ++i)
    for (int j = 0; j < 4; ++j) acc[i][j] = zero;

  for (int k0 = 0; k0 < K; k0 += 64) {
    __syncthreads();
    for (int it = 0; it < 4; ++it) {
      int o = (tid + it * 256) << 4;              // 0..16K-16
      int row = o >> 7, c = (o >> 4) & 7;
      int sw = swz_chunk(row, c) << 4;            // pre-swizzled source chunk
      gload_lds16((const char*)A + (((size_t)(tm + row) * K + k0) << 1) + sw, (char*)As + o);
      gload_lds16((const char*)B + (((size_t)(tn + row) * K + k0) << 1) + sw, (char*)Bs + o);
    }
    __syncthreads();
    for (int ks = 0; ks < 2; ++ks) {
      short8 af[4], bfr[4];
      for (int mi = 0; mi < 4; ++mi) {
        int row = wr * 64 + mi * 16 + l15;
        af[mi] = *(const short8*)((const char*)As + row * 128 +
                                  (swz_chunk(row, ks * 4 + lhi) << 4));
      }
      for (int ni = 0; ni < 4; ++ni) {
        int row = wc * 64 + ni * 16 + l15;
        bfr[ni] = *(const short8*)((const char*)Bs + row * 128 +
                                   (swz_chunk(row, ks * 4 + lhi) << 4));
      }
      for (int mi = 0; mi < 4; ++mi)
        for (int ni = 0; ni < 4; ++ni)
          acc[mi][ni] = MFMA16(af[mi], bfr[ni], acc[mi][ni]);
    }
  }

  for (int mi = 0; mi < 4; ++mi)
    for (int ni = 0; ni < 4; ++ni)
      for (int j = 0; j < 4; ++j) {
        int m = tm + wr * 64 + mi * 16 + lhi * 4 + j;   // token index
        int n = tn + wc * 64 + ni * 16 + l15;           // 0..767 within segment
        float v = (acc[mi][ni][j] + bias[n]) * scale;
        int b = m >> 12, s = m & 4095, h = n >> 6, d = n & 63;
        dst[(((size_t)(b * 12 + h) * 4096 + s) << 6) + d] = __float2bfloat16(v);
      }
}

// ------------------------------------------------------------ out-proj GEMM --
// 128x64 tiles, BK=64, swizzled LDS as above.
__global__ __launch_bounds__(256, 4) void gemm_wo(
    const bf16* __restrict__ A, const bf16* __restrict__ B,
    const float* __restrict__ bias, float* __restrict__ C) {
  __shared__ bf16 As[128 * 64];   // 16KB
  __shared__ bf16 Bs[64 * 64];    // 8KB
  const int tid = threadIdx.x;
  const int lane = tid & 63, wid = tid >> 6;
  const int l15 = lane & 15, lhi = lane >> 4;
  const int tm = blockIdx.x * 128, tn = blockIdx.y * 64;
  const int K = 768;

  f32x4 zero = {0.f, 0.f, 0.f, 0.f};
  f32x4 acc[2][4];
  for (int i = 0; i < 2; ++i)
    for (int j = 0; j < 4; ++j) acc[i][j] = zero;

  for (int k0 = 0; k0 < K; k0 += 64) {
    __syncthreads();
    for (int it = 0; it < 4; ++it) {
      int o = (tid + it * 256) << 4;
      int row = o >> 7, c = (o >> 4) & 7;
      int sw = swz_chunk(row, c) << 4;
      gload_lds16((const char*)A + (((size_t)(tm + row) * K + k0) << 1) + sw, (char*)As + o);
    }
    for (int it = 0; it < 2; ++it) {
      int o = (tid + it * 256) << 4;              // 0..8K-16
      int row = o >> 7, c = (o >> 4) & 7;
      int sw = swz_chunk(row, c) << 4;
      gload_lds16((const char*)B + (((size_t)(tn + row) * K + k0) << 1) + sw, (char*)Bs + o);
    }
    __syncthreads();
    for (int ks = 0; ks < 2; ++ks) {
      short8 af[2], bfr[4];
      for (int mi = 0; mi < 2; ++mi) {
        int row = wid * 32 + mi * 16 + l15;
        af[mi] = *(const short8*)((const char*)As + row * 128 +
                                  (swz_chunk(row, ks * 4 + lhi) << 4));
      }
      for (int ni = 0; ni < 4; ++ni) {
        int row = ni * 16 + l15;
        bfr[ni] = *(const short8*)((const char*)Bs + row * 128 +
                                   (swz_chunk(row, ks * 4 + lhi) << 4));
      }
      for (int mi = 0; mi < 2; ++mi)
        for (int ni = 0; ni < 4; ++ni)
          acc[mi][ni] = MFMA16(af[mi], bfr[ni], acc[mi][ni]);
    }
  }

  for (int mi = 0; mi < 2; ++mi)
    for (int ni = 0; ni < 4; ++ni)
      for (int j = 0; j < 4; ++j) {
        int m = tm + wid * 32 + mi * 16 + lhi * 4 + j;
        int n = tn + ni * 16 + l15;
        C[(size_t)m * 768 + n] = acc[mi][ni][j] + bias[n];
      }
}

// ------------------------------------------------------------- V transpose ---
// Vh [bh][4096][64] -> VTh [bh][64][4096], 64-token tiles. Write side packs
// token-pairs as b32 (round-5-verified mapping), halving LDS write instrs.
__global__ __launch_bounds__(256) void transpose_v(const bf16* __restrict__ Vh,
                                                   bf16* __restrict__ VTh) {
  __shared__ bf16 T[64 * 64];   // [d][kv] swizzled 16B chunks
  const int tid = threadIdx.x;
  const int bh = blockIdx.x >> 6;        // 0..23
  const int t = blockIdx.x & 63;         // token tile
  const char* src = (const char*)(Vh + ((size_t)bh * 4096 + t * 64) * 64);
  char* dst = (char*)(VTh + ((size_t)bh * 64) * 4096 + t * 64);

  const int rp = tid & 31, cc = tid >> 5;   // row-pair, d-chunk
  uint4 va = *(const uint4*)(src + (2 * rp) * 128 + cc * 16);
  uint4 vb = *(const uint4*)(src + (2 * rp + 1) * 128 + cc * 16);
  unsigned short a16[8], b16[8];
  __builtin_memcpy(a16, &va, 16);
  __builtin_memcpy(b16, &vb, 16);
#pragma unroll
  for (int jj = 0; jj < 8; ++jj) {
    uint32_t w = (uint32_t)a16[jj] | ((uint32_t)b16[jj] << 16);
    *(uint32_t*)((char*)T + (cc * 8 + jj) * 128 + (((rp >> 2) ^ jj) << 4) +
                 ((rp & 3) << 2)) = w;
  }
  __syncthreads();
  for (int it = 0; it < 2; ++it) {
    int idx = tid + it * 256;
    int d = idx >> 3, c = idx & 7;       // tokens c*8..c*8+7 of row d
    uint4 vv = *(const uint4*)((const char*)T + d * 128 + (swz_chunk(d, c) << 4));
    *(uint4*)(dst + (size_t)d * 8192 + c * 16) = vv;
  }
}

// --------------------------------------------------------------- attention ---
// Round-9 proven schedule (stage-next -> QK -> exp -> PV -> barrier) + T1
// bijective XCD swizzle: all 32 q-tile blocks of a head land on ONE XCD
// (3 heads/XCD = 3MB K+V working set, L2-resident per XCD).
__global__ __launch_bounds__(256, 3) void attn_kernel(
    const bf16* __restrict__ Qh, const bf16* __restrict__ Kh,
    const bf16* __restrict__ VTh, bf16* __restrict__ AO) {
  __shared__ float4 smem4[34816 / 16];   // union: K/V bufs (32KB) | OX (34KB)
  char* smraw = (char*)smem4;
#define KT(b) (smraw + (b) * 8192)
#define VT(b) (smraw + 16384 + (b) * 8192)
  float* OX = (float*)smraw;             // [2 qsub][64 lane][68]

  const int tid = threadIdx.x;
  const int lane = tid & 63, wid = tid >> 6;
  const int l31 = lane & 31, h = lane >> 5;
  const int qsub = wid & 1, kvh = wid >> 1;

  // XCD swizzle (blocks dispatch round-robin over 8 XCDs): block i runs on
  // XCD i&7; give it head (i&7)*3 + (i>>3)/32 so each head's 32 q-tiles
  // share one XCD's L2. Bijective: 768 = 8 * 3 * 32.
  const int i = blockIdx.x;
  const int xcd = i & 7, slot = i >> 3;
  const int bh = xcd * 3 + (slot >> 5);  // 0..23 = b*12+head
  const int qt = slot & 31;

  const size_t hb = (size_t)bh * 4096 * 64;
  const bf16* Qb = Qh + hb;
  const bf16* Kb = Kh + hb;
  const char* Vg0 = (const char*)(VTh + hb);   // V^T: row d stride 8192 B
  const int qb = qt * 128 + qsub * 64;

  short8 qf[2][4];
#pragma unroll
  for (int j = 0; j < 2; ++j)
#pragma unroll
    for (int ki = 0; ki < 4; ++ki)
      qf[j][ki] = *(const short8*)((const char*)Qb + (size_t)(qb + 32 * j + l31) * 128 +
                                   ki * 32 + h * 16);

  f32x16 z16;
  for (int i2 = 0; i2 < 16; ++i2) z16[i2] = 0.f;
  f32x16 o00 = z16, o01 = z16, o10 = z16, o11 = z16;
  float psum0 = 0.f, psum1 = 0.f;

  const int krow = kvh * 32 + l31;

  for (int it = 0; it < 2; ++it) {
    int o = (tid + it * 256) << 4;
    int row = o >> 7, c = (o >> 4) & 7;
    int sw = swz_chunk(row, c) << 4;
    gload_lds16((const char*)Kb + row * 128 + sw, KT(0) + o);
    gload_lds16(Vg0 + row * 8192 + sw, VT(0) + o);
  }
  __syncthreads();

  int cur = 0;
  for (int kt = 0; kt < 64; ++kt) {
    if (kt < 63) {
      const char* Kg = (const char*)(Kb + (size_t)(kt + 1) * 4096);
      const char* Vg = Vg0 + (size_t)(kt + 1) * 128;
      char* Kd = KT(cur ^ 1);
      char* Vd = VT(cur ^ 1);
      for (int it = 0; it < 2; ++it) {
        int o = (tid + it * 256) << 4;
        int row = o >> 7, c = (o >> 4) & 7;
        int sw = swz_chunk(row, c) << 4;
        gload_lds16(Kg + row * 128 + sw, Kd + o);
        gload_lds16(Vg + row * 8192 + sw, Vd + o);
      }
    }

    const char* Kl = KT(cur);
    const char* Vl = VT(cur);

    f32x16 s0, s1;
    __builtin_amdgcn_s_setprio(1);
    {
      short8 kf = *(const short8*)(Kl + krow * 128 + (swz_chunk(krow, h) << 4));
      s0 = MFMA32(kf, qf[0][0], z16);
      s1 = MFMA32(kf, qf[1][0], z16);
    }
#pragma unroll
    for (int ki = 1; ki < 4; ++ki) {
      short8 kf = *(const short8*)(Kl + krow * 128 + (swz_chunk(krow, 2 * ki + h) << 4));
      s0 = MFMA32(kf, qf[0][ki], s0);
      s1 = MFMA32(kf, qf[1][ki], s1);
    }
    __builtin_amdgcn_s_setprio(0);

    short8 pb[2][2];
#pragma unroll
    for (int j = 0; j < 2; ++j) {
#pragma unroll
      for (int kk = 0; kk < 2; ++kk) {
        float p[8];
#pragma unroll
        for (int e = 0; e < 8; ++e)
          p[e] = __builtin_amdgcn_exp2f(j ? s1[8 * kk + e] : s0[8 * kk + e]);
        float ps = ((p[0] + p[1]) + (p[2] + p[3])) + ((p[4] + p[5]) + (p[6] + p[7]));
        if (j) psum1 += ps; else psum0 += ps;
        uint32_t A0 = cvtpk(p[0], p[1]), A1 = cvtpk(p[2], p[3]);
        uint32_t B0 = cvtpk(p[4], p[5]), B1 = cvtpk(p[6], p[7]);
        pl32swap(A0, B0);
        pl32swap(A1, B1);
        uint32_t w[4] = {A0, A1, B0, B1};
        short8 frag;
        __builtin_memcpy(&frag, w, 16);
        pb[j][kk] = frag;
      }
    }

    __builtin_amdgcn_s_setprio(1);
#pragma unroll
    for (int kk = 0; kk < 2; ++kk) {
      short8 v0 = *(const short8*)(Vl + l31 * 128 +
                                   (swz_chunk(l31, 4 * kvh + 2 * kk + h) << 4));
      short8 v1 = *(const short8*)(Vl + (32 + l31) * 128 +
                                   (swz_chunk(32 + l31, 4 * kvh + 2 * kk + h) << 4));
      o00 = MFMA32(v0, pb[0][kk], o00);
      o01 = MFMA32(v0, pb[1][kk], o01);
      o10 = MFMA32(v1, pb[0][kk], o10);
      o11 = MFMA32(v1, pb[1][kk], o11);
    }
    __builtin_amdgcn_s_setprio(0);

    __syncthreads();
    cur ^= 1;
  }

  psum0 += __shfl_xor(psum0, 32);
  psum1 += __shfl_xor(psum1, 32);

  float* W = OX + (size_t)(qsub * 64 + lane) * 68;
  if (kvh == 1) {
#pragma unroll
    for (int g = 0; g < 4; ++g) {
      *(float4*)(W + 0 * 16 + 4 * g) = make_float4(o00[4*g], o00[4*g+1], o00[4*g+2], o00[4*g+3]);
      *(float4*)(W + 1 * 16 + 4 * g) = make_float4(o01[4*g], o01[4*g+1], o01[4*g+2], o01[4*g+3]);
      *(float4*)(W + 2 * 16 + 4 * g) = make_float4(o10[4*g], o10[4*g+1], o10[4*g+2], o10[4*g+3]);
      *(float4*)(W + 3 * 16 + 4 * g) = make_float4(o11[4*g], o11[4*g+1], o11[4*g+2], o11[4*g+3]);
    }
    W[64] = psum0;
    W[65] = psum1;
  }
  __syncthreads();
  if (kvh == 0) {
#pragma unroll
    for (int g = 0; g < 4; ++g) {
      float4 a0 = *(const float4*)(W + 0 * 16 + 4 * g);
      float4 a1 = *(const float4*)(W + 1 * 16 + 4 * g);
      float4 a2 = *(const float4*)(W + 2 * 16 + 4 * g);
      float4 a3 = *(const float4*)(W + 3 * 16 + 4 * g);
      o00[4*g] += a0.x; o00[4*g+1] += a0.y; o00[4*g+2] += a0.z; o00[4*g+3] += a0.w;
      o01[4*g] += a1.x; o01[4*g+1] += a1.y; o01[4*g+2] += a1.z; o01[4*g+3] += a1.w;
      o10[4*g] += a2.x; o10[4*g+1] += a2.y; o10[4*g+2] += a2.z; o10[4*g+3] += a2.w;
      o11[4*g] += a3.x; o11[4*g+1] += a3.y; o11[4*g+2] += a3.z; o11[4*g+3] += a3.w;
    }
    psum0 += W[64];
    psum1 += W[65];
    float pinv0 = 1.0f / psum0;
    float pinv1 = 1.0f / psum1;

    const int b = bh / 12, hd = bh % 12;
#pragma unroll
    for (int j = 0; j < 2; ++j) {
      int q = qb + 32 * j + l31;
      char* base = (char*)AO + (((size_t)(b * 4096 + q)) * 768 + hd * 64) * 2;
      float pv = j ? pinv1 : pinv0;
#pragma unroll
      for (int t = 0; t < 2; ++t) {
#pragma unroll
        for (int u = 0; u < 4; ++u) {
          ushort4 us;
          float v0 = (t ? (j ? o11[4*u+0] : o10[4*u+0]) : (j ? o01[4*u+0] : o00[4*u+0]));
          float v1 = (t ? (j ? o11[4*u+1] : o10[4*u+1]) : (j ? o01[4*u+1] : o00[4*u+1]));
          float v2 = (t ? (j ? o11[4*u+2] : o10[4*u+2]) : (j ? o01[4*u+2] : o00[4*u+2]));
          float v3 = (t ? (j ? o11[4*u+3] : o10[4*u+3]) : (j ? o01[4*u+3] : o00[4*u+3]));
          us.x = f2bf(v0 * pv);
          us.y = f2bf(v1 * pv);
          us.z = f2bf(v2 * pv);
          us.w = f2bf(v3 * pv);
          int d0 = 32 * t + 8 * u + 4 * h;
          *(ushort4*)(base + d0 * 2) = us;
        }
      }
    }
  }
#undef KT
#undef VT
}

// ------------------------------------------------------------------ launch ---
extern "C" void kernel_launch(void* const* d_in, const int* in_sizes, int n_in,
                              void* d_out, int out_size, void* d_ws, size_t ws_size,
                              hipStream_t stream) {
  (void)in_sizes; (void)n_in; (void)out_size; (void)ws_size;
  const float* x  = (const float*)d_in[0];
  const float* Wq = (const float*)d_in[1];
  const float* bq = (const float*)d_in[2];
  const float* Wk = (const float*)d_in[3];
  const float* bk = (const float*)d_in[4];
  const float* Wv = (const float*)d_in[5];
  const float* bv = (const float*)d_in[6];
  const float* Wo = (const float*)d_in[7];
  const float* bo = (const float*)d_in[8];

  char* ws = (char*)d_ws;
  bf16* Qh  = (bf16*)(ws + 0);           // [24][4096][64]
  bf16* Kh  = (bf16*)(ws + 12582912);
  bf16* Vh  = (bf16*)(ws + 25165824);    // V head-split; later reused as AO
  bf16* xb  = (bf16*)(ws + 37748736);    // x bf16; later reused as V^T
  bf16* Wqb = (bf16*)(ws + 50331648);
  bf16* Wkb = (bf16*)(ws + 51511296);
  bf16* Wvb = (bf16*)(ws + 52690944);
  bf16* Wob = (bf16*)(ws + 53870592);    // end ~55.05 MB
  bf16* VTh = xb;                        // V^T [24][64][4096] (xb dead then)
  bf16* AO  = Vh;                        // attn out (Vh dead then)

  cvt_all<<<8448, 256, 0, stream>>>(x, Wq, Wk, Wv, Wo, xb, Wqb, Wkb, Wvb, Wob);

  const float SQ = 0.125f * 1.4426950408889634f;  // 1/sqrt(64) * log2(e)
  dim3 gq(64, 18);
  gemm_qkv<<<gq, 256, 0, stream>>>(xb, Wqb, Wkb, Wvb, bq, bk, bv,
                                   Qh, Kh, Vh, SQ);
  transpose_v<<<1536, 256, 0, stream>>>(Vh, VTh);
  attn_kernel<<<768, 256, 0, stream>>>(Qh, Kh, VTh, AO);
  dim3 gw(64, 12);
  gemm_wo<<<gw, 256, 0, stream>>>(AO, Wob, bo, (float*)d_out);
}